// Round 8
// baseline (240.495 us; speedup 1.0000x reference)
//
#include <hip/hip_runtime.h>

typedef float v2f __attribute__((ext_vector_type(2)));

constexpr int DIM = 6;
constexpr int PAIRS = 2;          // 4 rows per thread
constexpr float NEG = 0.01f;

// One 6x6 layer on PAIRS packed row-pairs (v_pk_* ops). Weights/bias
// wave-uniform -> SGPR; each s_load'ed weight feeds PAIRS pk_fmas.
// FOLD_RES starts the accumulator at res+bias (residual fused, free).
template<bool RELU, bool FOLD_RES>
__device__ __forceinline__ void layerN(const float* __restrict__ W,
                                       const float* __restrict__ b,
                                       v2f (&x)[PAIRS][DIM],
                                       const v2f (&res)[PAIRS][DIM]) {
    v2f y[PAIRS][DIM];
    #pragma unroll
    for (int j = 0; j < DIM; ++j) {
        const float bj = b[j];
        #pragma unroll
        for (int p = 0; p < PAIRS; ++p) {
            v2f acc = FOLD_RES ? (res[p][j] + (v2f){bj, bj}) : (v2f){bj, bj};
            #pragma unroll
            for (int k = 0; k < DIM; ++k) {
                const float wjk = W[j * DIM + k];
                acc = __builtin_elementwise_fma((v2f){wjk, wjk}, x[p][k], acc);
            }
            if (RELU)
                acc = __builtin_elementwise_max(acc, acc * (v2f){NEG, NEG});
            y[p][j] = acc;
        }
    }
    #pragma unroll
    for (int p = 0; p < PAIRS; ++p)
        #pragma unroll
        for (int j = 0; j < DIM; ++j) x[p][j] = y[p][j];
}

__device__ __forceinline__ void run_net(const float* __restrict__ Ws,
                                        const float* __restrict__ bs,
                                        v2f (&w)[PAIRS][DIM]) {
    #pragma unroll 1
    for (int blk = 0; blk < 4; ++blk) {
        const float* Wb = Ws + (size_t)blk * 144;
        const float* bb = bs + (size_t)blk * 24;
        v2f res[PAIRS][DIM];
        #pragma unroll
        for (int p = 0; p < PAIRS; ++p)
            #pragma unroll
            for (int k = 0; k < DIM; ++k) res[p][k] = w[p][k];
        layerN<true , false>(Wb +   0, bb +  0, w, res);
        layerN<true , false>(Wb +  36, bb +  6, w, res);
        layerN<true , false>(Wb +  72, bb + 12, w, res);
        layerN<false, true >(Wb + 108, bb + 18, w, res);   // acc = res + b
    }
    layerN<true , false>(Ws + 16 * 36, bs + 16 * 6, w, w);
    layerN<true , false>(Ws + 17 * 36, bs + 17 * 6, w, w);
    layerN<false, false>(Ws + 18 * 36, bs + 18 * 6, w, w);
}

__global__ __launch_bounds__(128, 8) void mlp19_kernel(
    const float* __restrict__ X,
    const float* __restrict__ Ws,
    const float* __restrict__ bs,
    const float* __restrict__ bounds,
    float* __restrict__ out, int B)
{
    const int g  = blockIdx.x * blockDim.x + threadIdx.x;
    const int r0 = 2 * PAIRS * g;
    if (r0 >= B) return;

    float sc[DIM], sh[DIM];
    #pragma unroll
    for (int k = 0; k < DIM; ++k) {
        const float lo = bounds[2 * k], hi = bounds[2 * k + 1];
        const float inv = 1.0f / (hi - lo);
        sc[k] = inv;
        sh[k] = -lo * inv;
    }

    if (r0 + 2 * PAIRS - 1 < B) {
        const float* xp = X + (size_t)r0 * DIM;    // 24 contiguous floats
        v2f w[PAIRS][DIM];
        #pragma unroll
        for (int p = 0; p < PAIRS; ++p) {
            const float4 a = *reinterpret_cast<const float4*>(xp + p * 12 + 0);
            const float4 b = *reinterpret_cast<const float4*>(xp + p * 12 + 4);
            const float4 c = *reinterpret_cast<const float4*>(xp + p * 12 + 8);
            w[p][0] = (v2f){a.x, b.z}; w[p][1] = (v2f){a.y, b.w};
            w[p][2] = (v2f){a.z, c.x}; w[p][3] = (v2f){a.w, c.y};
            w[p][4] = (v2f){b.x, c.z}; w[p][5] = (v2f){b.y, c.w};
        }
        #pragma unroll
        for (int p = 0; p < PAIRS; ++p)
            #pragma unroll
            for (int k = 0; k < DIM; ++k)
                w[p][k] = __builtin_elementwise_fma(
                    w[p][k], (v2f){sc[k], sc[k]}, (v2f){sh[k], sh[k]});

        run_net(Ws, bs, w);

        float* op = out + (size_t)r0 * DIM;
        #pragma unroll
        for (int p = 0; p < PAIRS; ++p) {
            float4 o0 = {w[p][0].x, w[p][1].x, w[p][2].x, w[p][3].x};
            float4 o1 = {w[p][4].x, w[p][5].x, w[p][0].y, w[p][1].y};
            float4 o2 = {w[p][2].y, w[p][3].y, w[p][4].y, w[p][5].y};
            *reinterpret_cast<float4*>(op + p * 12 + 0) = o0;
            *reinterpret_cast<float4*>(op + p * 12 + 4) = o1;
            *reinterpret_cast<float4*>(op + p * 12 + 8) = o2;
        }
    } else {
        for (int r = r0; r < B; ++r) {
            const float* xp = X + (size_t)r * DIM;
            v2f w[PAIRS][DIM];
            #pragma unroll
            for (int k = 0; k < DIM; ++k) {
                const float t = fmaf(xp[k], sc[k], sh[k]);
                #pragma unroll
                for (int p = 0; p < PAIRS; ++p) w[p][k] = (v2f){t, t};
            }
            run_net(Ws, bs, w);
            float* op = out + (size_t)r * DIM;
            #pragma unroll
            for (int k = 0; k < DIM; ++k) op[k] = w[0][k].x;
        }
    }
}

extern "C" void kernel_launch(void* const* d_in, const int* in_sizes, int n_in,
                              void* d_out, int out_size, void* d_ws, size_t ws_size,
                              hipStream_t stream) {
    const float* X      = (const float*)d_in[0];
    const float* Ws     = (const float*)d_in[1];
    const float* bs     = (const float*)d_in[2];
    const float* bounds = (const float*)d_in[3];
    float* out = (float*)d_out;

    const int B = in_sizes[0] / DIM;
    const int block = 128;                          // 2 waves/wg: clears wg/CU cap
    const int rows_per_block = block * 2 * PAIRS;   // 512
    const int grid = (B + rows_per_block - 1) / rows_per_block;   // 8192
    hipLaunchKernelGGL(mlp19_kernel, dim3(grid), dim3(block), 0, stream,
                       X, Ws, bs, bounds, out, B);
}

// Round 9
// 207.389 us; speedup vs baseline: 1.1596x; 1.1596x over previous
//
#include <hip/hip_runtime.h>

typedef float v2f __attribute__((ext_vector_type(2)));

constexpr int DIM = 6;
constexpr int PAIRS = 2;          // 4 rows per thread
constexpr float NEG = 0.01f;

// One 6x6 layer on PAIRS packed row-pairs (v_pk_* ops). Weights/bias
// wave-uniform -> SGPR; each s_load'ed weight feeds PAIRS pk_fmas.
// FOLD_RES starts the accumulator at res+bias (residual fused, free).
template<bool RELU, bool FOLD_RES>
__device__ __forceinline__ void layerN(const float* __restrict__ W,
                                       const float* __restrict__ b,
                                       v2f (&x)[PAIRS][DIM],
                                       const v2f (&res)[PAIRS][DIM]) {
    v2f y[PAIRS][DIM];
    #pragma unroll
    for (int j = 0; j < DIM; ++j) {
        const float bj = b[j];
        #pragma unroll
        for (int p = 0; p < PAIRS; ++p) {
            v2f acc = FOLD_RES ? (res[p][j] + (v2f){bj, bj}) : (v2f){bj, bj};
            #pragma unroll
            for (int k = 0; k < DIM; ++k) {
                const float wjk = W[j * DIM + k];
                acc = __builtin_elementwise_fma((v2f){wjk, wjk}, x[p][k], acc);
            }
            if (RELU)
                acc = __builtin_elementwise_max(acc, acc * (v2f){NEG, NEG});
            y[p][j] = acc;
        }
    }
    #pragma unroll
    for (int p = 0; p < PAIRS; ++p)
        #pragma unroll
        for (int j = 0; j < DIM; ++j) x[p][j] = y[p][j];
}

__device__ __forceinline__ void run_net(const float* __restrict__ Ws,
                                        const float* __restrict__ bs,
                                        v2f (&w)[PAIRS][DIM]) {
    #pragma unroll 1
    for (int blk = 0; blk < 4; ++blk) {
        const float* Wb = Ws + (size_t)blk * 144;
        const float* bb = bs + (size_t)blk * 24;
        v2f res[PAIRS][DIM];
        #pragma unroll
        for (int p = 0; p < PAIRS; ++p)
            #pragma unroll
            for (int k = 0; k < DIM; ++k) res[p][k] = w[p][k];
        layerN<true , false>(Wb +   0, bb +  0, w, res);
        layerN<true , false>(Wb +  36, bb +  6, w, res);
        layerN<true , false>(Wb +  72, bb + 12, w, res);
        layerN<false, true >(Wb + 108, bb + 18, w, res);   // acc = res + b
    }
    layerN<true , false>(Ws + 16 * 36, bs + 16 * 6, w, w);
    layerN<true , false>(Ws + 17 * 36, bs + 17 * 6, w, w);
    layerN<false, false>(Ws + 18 * 36, bs + 18 * 6, w, w);
}

__global__ __launch_bounds__(128, 4) void mlp19_kernel(
    const float* __restrict__ X,
    const float* __restrict__ Ws,
    const float* __restrict__ bs,
    const float* __restrict__ bounds,
    float* __restrict__ out, int B)
{
    const int g  = blockIdx.x * blockDim.x + threadIdx.x;
    const int r0 = 2 * PAIRS * g;
    if (r0 >= B) return;

    float sc[DIM], sh[DIM];
    #pragma unroll
    for (int k = 0; k < DIM; ++k) {
        const float lo = bounds[2 * k], hi = bounds[2 * k + 1];
        const float inv = 1.0f / (hi - lo);
        sc[k] = inv;
        sh[k] = -lo * inv;
    }

    if (r0 + 2 * PAIRS - 1 < B) {
        const float* xp = X + (size_t)r0 * DIM;    // 24 contiguous floats
        v2f w[PAIRS][DIM];
        #pragma unroll
        for (int p = 0; p < PAIRS; ++p) {
            const float4 a = *reinterpret_cast<const float4*>(xp + p * 12 + 0);
            const float4 b = *reinterpret_cast<const float4*>(xp + p * 12 + 4);
            const float4 c = *reinterpret_cast<const float4*>(xp + p * 12 + 8);
            w[p][0] = (v2f){a.x, b.z}; w[p][1] = (v2f){a.y, b.w};
            w[p][2] = (v2f){a.z, c.x}; w[p][3] = (v2f){a.w, c.y};
            w[p][4] = (v2f){b.x, c.z}; w[p][5] = (v2f){b.y, c.w};
        }
        #pragma unroll
        for (int p = 0; p < PAIRS; ++p)
            #pragma unroll
            for (int k = 0; k < DIM; ++k)
                w[p][k] = __builtin_elementwise_fma(
                    w[p][k], (v2f){sc[k], sc[k]}, (v2f){sh[k], sh[k]});

        run_net(Ws, bs, w);

        float* op = out + (size_t)r0 * DIM;
        #pragma unroll
        for (int p = 0; p < PAIRS; ++p) {
            float4 o0 = {w[p][0].x, w[p][1].x, w[p][2].x, w[p][3].x};
            float4 o1 = {w[p][4].x, w[p][5].x, w[p][0].y, w[p][1].y};
            float4 o2 = {w[p][2].y, w[p][3].y, w[p][4].y, w[p][5].y};
            *reinterpret_cast<float4*>(op + p * 12 + 0) = o0;
            *reinterpret_cast<float4*>(op + p * 12 + 4) = o1;
            *reinterpret_cast<float4*>(op + p * 12 + 8) = o2;
        }
    } else {
        for (int r = r0; r < B; ++r) {
            const float* xp = X + (size_t)r * DIM;
            v2f w[PAIRS][DIM];
            #pragma unroll
            for (int k = 0; k < DIM; ++k) {
                const float t = fmaf(xp[k], sc[k], sh[k]);
                #pragma unroll
                for (int p = 0; p < PAIRS; ++p) w[p][k] = (v2f){t, t};
            }
            run_net(Ws, bs, w);
            float* op = out + (size_t)r * DIM;
            #pragma unroll
            for (int k = 0; k < DIM; ++k) op[k] = w[0][k].x;
        }
    }
}

extern "C" void kernel_launch(void* const* d_in, const int* in_sizes, int n_in,
                              void* d_out, int out_size, void* d_ws, size_t ws_size,
                              hipStream_t stream) {
    const float* X      = (const float*)d_in[0];
    const float* Ws     = (const float*)d_in[1];
    const float* bs     = (const float*)d_in[2];
    const float* bounds = (const float*)d_in[3];
    float* out = (float*)d_out;

    const int B = in_sizes[0] / DIM;
    const int block = 128;                          // 2 waves/wg
    const int rows_per_block = block * 2 * PAIRS;   // 512
    const int grid = (B + rows_per_block - 1) / rows_per_block;   // 8192
    hipLaunchKernelGGL(mlp19_kernel, dim3(grid), dim3(block), 0, stream,
                       X, Ws, bs, bounds, out, B);
}